// Round 2
// baseline (709.709 us; speedup 1.0000x reference)
//
#include <hip/hip_runtime.h>
#include <hip/hip_bf16.h>
#include <math.h>

// Problem constants (fixed by setup_inputs)
#define S3    128
#define NB    2
#define CF    16
#define CHS   (S3*S3*S3)          // 2097152 per-channel voxels
#define NVOX  (NB*CHS)            // 4194304
#define NW    (NVOX/64)           // 65536 bit-words per mask
#define CAP   1048576             // candidate buffer entries

typedef unsigned long long u64;
typedef unsigned int u32;

// ---- workspace layout (bytes) ----
// zeroed region: acc + stdn + scan + hist(64K bins) + hib
#define ACC_OFF    0                       // double[32]
#define STD_OFF    512                     // float[16]
#define SCAN_OFF   576                     // u32[32]
#define HIST_OFF   1024                    // u32[65536] = 256 KB
#define HIB_OFF    (HIST_OFF + 65536*4)    // 263168, u64[NW]
#define ZERO_BYTES (HIB_OFF + NW*8)        // 787456
#define POSB_OFF   ZERO_BYTES
#define NEGB_OFF   (POSB_OFF + NW*8)
#define DTMP_OFF   (NEGB_OFF + NW*8)       // 2 masks
#define DILP_OFF   (DTMP_OFF + 2*NW*8)
#define DILH_OFF   (DILP_OFF + NW*8)
#define CAND_OFF   (DILH_OFF + NW*8)       // u64[CAP]
#define COS_OFF    (CAND_OFF + CAP*8)      // float[NVOX] (16-byte aligned)

// accumulator (doubles): 0..15 fs; 16..18 n0,n1,n2; 19 ce; 20..22 S_c; 23..25 T_c;
// 26 s_pos; 27 s_easy; 28 c_easy; 29 s_fneg; 30 c_fneg

__device__ __forceinline__ double wave_red(double x) {
    for (int o = 32; o > 0; o >>= 1) x += __shfl_down(x, o);
    return x;
}
__device__ __forceinline__ u32 mono_key(float f) {
    u32 u = __float_as_uint(f);
    return (u & 0x80000000u) ? ~u : (u | 0x80000000u);
}
// deposit 16 bits to every 4th bit position of a u64
__device__ __forceinline__ u64 spread4(u32 x16) {
    u64 x = (u64)(x16 & 0xFFFFu);
    x = (x | (x << 24)) & 0x000000FF000000FFull;
    x = (x | (x << 12)) & 0x000F000F000F000Full;
    x = (x | (x << 6))  & 0x0303030303030303ull;
    x = (x | (x << 3))  & 0x1111111111111111ull;
    return x;
}

// ---- pass 1 (fused): masks + class counts + pos-feature sums + CE/dice sums ----
__global__ __launch_bounds__(256) void k_main(const float* __restrict__ feat,
        const float* __restrict__ net, const int* __restrict__ tgt,
        u64* __restrict__ posb, u64* __restrict__ negb, double* __restrict__ acc)
{
    int tid = blockIdx.x * 256 + threadIdx.x;
    const int gstride = gridDim.x * 256;
    const int lane = threadIdx.x & 63;
    float fs[16];
    #pragma unroll
    for (int c = 0; c < 16; c++) fs[c] = 0.f;
    float ce = 0.f, s0 = 0.f, s1 = 0.f, s2 = 0.f, ta0 = 0.f, ta1 = 0.f, ta2 = 0.f;
    int n0 = 0, n1 = 0, n2 = 0;

    for (int idx = tid; idx < NVOX / 4; idx += gstride) {
        const int v4 = idx << 2;
        const int b = v4 >> 21;
        const int4 tv = *(const int4*)(tgt + v4);
        const int T[4] = {tv.x, tv.y, tv.z, tv.w};
        u32 nib_p = (u32)(T[0]==1) | ((u32)(T[1]==1)<<1) | ((u32)(T[2]==1)<<2) | ((u32)(T[3]==1)<<3);
        u32 nib_n = (u32)(T[0]==0) | ((u32)(T[1]==0)<<1) | ((u32)(T[2]==0)<<2) | ((u32)(T[3]==0)<<3);
        int pp = __popc(nib_p), nn_ = __popc(nib_n);
        n1 += pp; n0 += nn_; n2 += 4 - pp - nn_;

        // pack bitmask words (wave covers 256 consecutive voxels = 4 u64 words)
        u64 bp0 = __ballot(nib_p & 1), bp1 = __ballot(nib_p & 2),
            bp2 = __ballot(nib_p & 4), bp3 = __ballot(nib_p & 8);
        u64 bn0 = __ballot(nib_n & 1), bn1 = __ballot(nib_n & 2),
            bn2 = __ballot(nib_n & 4), bn3 = __ballot(nib_n & 8);
        if ((lane & 15) == 0) {
            int wsel = lane >> 4, sh = wsel << 4;
            u64 wp = spread4((u32)(bp0 >> sh)) | (spread4((u32)(bp1 >> sh)) << 1)
                   | (spread4((u32)(bp2 >> sh)) << 2) | (spread4((u32)(bp3 >> sh)) << 3);
            u64 wn = spread4((u32)(bn0 >> sh)) | (spread4((u32)(bn1 >> sh)) << 1)
                   | (spread4((u32)(bn2 >> sh)) << 2) | (spread4((u32)(bn3 >> sh)) << 3);
            int wi = ((idx - lane) >> 4) + wsel;
            posb[wi] = wp; negb[wi] = wn;
        }

        // CE + dice sums (3-class softmax on 4 voxels)
        const size_t nbase = (size_t)v4 + (size_t)b * (2u * CHS);
        float4 a0 = *(const float4*)(net + nbase);
        float4 a1 = *(const float4*)(net + nbase + CHS);
        float4 a2 = *(const float4*)(net + nbase + 2 * (size_t)CHS);
        const float X0[4] = {a0.x, a0.y, a0.z, a0.w};
        const float X1[4] = {a1.x, a1.y, a1.z, a1.w};
        const float X2[4] = {a2.x, a2.y, a2.z, a2.w};
        #pragma unroll
        for (int j = 0; j < 4; j++) {
            float x0 = X0[j], x1 = X1[j], x2 = X2[j];
            float m = fmaxf(x0, fmaxf(x1, x2));
            float e0 = expf(x0 - m), e1 = expf(x1 - m), e2 = expf(x2 - m);
            float sum = e0 + e1 + e2;
            float lse = m + logf(sum);
            int t = T[j];
            float xt = (t == 0) ? x0 : ((t == 1) ? x1 : x2);
            ce += lse - xt;
            float inv = 1.f / sum;
            float p0 = e0 * inv, p1 = e1 * inv, p2 = e2 * inv;
            s0 += p0; s1 += p1; s2 += p2;
            if (t == 0) ta0 += p0; else if (t == 1) ta1 += p1; else ta2 += p2;
        }

        // pos-feature channel sums (predicated FMA; per-thread partial <= 8 values)
        const float* fb = feat + (size_t)v4 + (size_t)b * ((size_t)(CF - 1) * CHS);
        float w0 = (float)(nib_p & 1), w1 = (float)((nib_p >> 1) & 1),
              w2 = (float)((nib_p >> 2) & 1), w3 = (float)((nib_p >> 3) & 1);
        #pragma unroll
        for (int c = 0; c < 16; c++) {
            float4 f = *(const float4*)(fb + (size_t)c * CHS);
            fs[c] += f.x * w0 + f.y * w1 + f.z * w2 + f.w * w3;
        }
    }

    __shared__ double red[4][26];
    double vals[26];
    #pragma unroll
    for (int c = 0; c < 16; c++) vals[c] = (double)fs[c];
    vals[16] = n0; vals[17] = n1; vals[18] = n2;
    vals[19] = ce; vals[20] = s0; vals[21] = s1; vals[22] = s2;
    vals[23] = ta0; vals[24] = ta1; vals[25] = ta2;
    int wid = threadIdx.x >> 6;
    #pragma unroll
    for (int i = 0; i < 26; i++) {
        double x = wave_red(vals[i]);
        if (lane == 0) red[wid][i] = x;
    }
    __syncthreads();
    if (threadIdx.x < 26) {
        double s = red[0][threadIdx.x] + red[1][threadIdx.x] + red[2][threadIdx.x] + red[3][threadIdx.x];
        atomicAdd(&acc[threadIdx.x], s);
    }
}

// ---- std_n from pos-feature sums ----
__global__ void k_std(const double* __restrict__ acc, float* __restrict__ stdn) {
    __shared__ float v[16];
    double cnt = acc[17];
    if (threadIdx.x < 16) {
        double mp = acc[threadIdx.x] / fmax(cnt, 1.0);
        v[threadIdx.x] = (cnt > 0.0) ? (float)mp : 0.0f;
    }
    __syncthreads();
    if (threadIdx.x == 0) {
        float n = 0;
        for (int c = 0; c < 16; c++) n += v[c] * v[c];
        n = fmaxf(sqrtf(n), 1e-12f);
        for (int c = 0; c < 16; c++) stdn[c] = v[c] / n;
    }
}

// ---- pass 2: cos_map + 64K-bin global histogram of negative keys ----
__global__ __launch_bounds__(256) void k_cos(const float* __restrict__ feat,
        const float* __restrict__ stdn, const u64* __restrict__ negb,
        float* __restrict__ cosm, u32* __restrict__ hist)
{
    __shared__ float sn[16];
    if (threadIdx.x < 16) sn[threadIdx.x] = stdn[threadIdx.x];
    __syncthreads();
    int tid = blockIdx.x * 256 + threadIdx.x;
    const int gstride = gridDim.x * 256;
    for (int idx = tid; idx < NVOX / 4; idx += gstride) {
        const int v4 = idx << 2;
        const int b = v4 >> 21;
        const float* fb = feat + (size_t)v4 + (size_t)b * ((size_t)(CF - 1) * CHS);
        float d0 = 0, d1 = 0, d2 = 0, d3 = 0, q0 = 0, q1 = 0, q2 = 0, q3 = 0;
        #pragma unroll
        for (int c = 0; c < 16; c++) {
            float4 f = *(const float4*)(fb + (size_t)c * CHS);
            float s = sn[c];
            d0 = fmaf(f.x, s, d0); q0 = fmaf(f.x, f.x, q0);
            d1 = fmaf(f.y, s, d1); q1 = fmaf(f.y, f.y, q1);
            d2 = fmaf(f.z, s, d2); q2 = fmaf(f.z, f.z, q2);
            d3 = fmaf(f.w, s, d3); q3 = fmaf(f.w, f.w, q3);
        }
        float c0 = d0 / fmaxf(sqrtf(q0), 1e-12f);
        float c1 = d1 / fmaxf(sqrtf(q1), 1e-12f);
        float c2 = d2 / fmaxf(sqrtf(q2), 1e-12f);
        float c3 = d3 / fmaxf(sqrtf(q3), 1e-12f);
        *(float4*)(cosm + v4) = make_float4(c0, c1, c2, c3);
        u32 nib = (u32)(negb[v4 >> 6] >> (v4 & 63)) & 0xFu;
        if (nib & 1) atomicAdd(&hist[mono_key(c0) >> 16], 1u);
        if (nib & 2) atomicAdd(&hist[mono_key(c1) >> 16], 1u);
        if (nib & 4) atomicAdd(&hist[mono_key(c2) >> 16], 1u);
        if (nib & 8) atomicAdd(&hist[mono_key(c3) >> 16], 1u);
    }
}

// ---- find bin containing the 250th key (descending) ----
__global__ void k_scanA(const u32* __restrict__ hist, u32* __restrict__ scan) {
    __shared__ u32 cs[256];
    u32 s = 0; int base = threadIdx.x * 256;
    for (int j = 0; j < 256; j++) s += hist[base + j];
    cs[threadIdx.x] = s;
    __syncthreads();
    if (threadIdx.x == 0) {
        u32 need = 250, cum = 0; int chunk = 0;
        for (int c = 255; c >= 0; c--) { if (cum + cs[c] >= need) { chunk = c; break; } cum += cs[c]; }
        int bin = chunk * 256;
        for (int bI = chunk * 256 + 255; bI >= chunk * 256; bI--) {
            if (cum + hist[bI] >= need) { bin = bI; break; }
            cum += hist[bI];
        }
        scan[0] = (u32)bin;        // binA
        scan[1] = need - cum;      // residual need within binA
    }
}

// ---- collect candidates (neg & key >= binA<<16) ----
__global__ __launch_bounds__(256) void k_collect(const float* __restrict__ cosm,
        const u64* __restrict__ negb, u32* __restrict__ scan, u64* __restrict__ cand)
{
    const u32 thr = scan[0] << 16;
    int tid = blockIdx.x * 256 + threadIdx.x;
    const int gstride = gridDim.x * 256;
    for (int idx = tid; idx < NVOX / 4; idx += gstride) {
        const int v4 = idx << 2;
        u32 nib = (u32)(negb[v4 >> 6] >> (v4 & 63)) & 0xFu;
        if (!nib) continue;
        float4 cv = *(const float4*)(cosm + v4);
        const float C[4] = {cv.x, cv.y, cv.z, cv.w};
        #pragma unroll
        for (int j = 0; j < 4; j++) {
            if ((nib >> j) & 1) {
                u32 key = mono_key(C[j]);
                if (key >= thr) {
                    u32 p = atomicAdd(&scan[4], 1u);
                    if (p < CAP) cand[p] = ((u64)key << 32) | (u32)(v4 + j);
                }
            }
        }
    }
}

// ---- single-block exact top-250 threshold + mark hi bits ----
__global__ __launch_bounds__(256) void k_select(const u64* __restrict__ cand,
        const u32* __restrict__ scan, u64* __restrict__ hib)
{
    __shared__ u32 h[256];
    __shared__ u32 eqlist[2048];
    __shared__ u32 eqc, sh_b1, sh_need2, sh_K, sh_need3;
    const u32 cnt = scan[4];
    const int n = (int)(cnt < CAP ? cnt : CAP);
    const u32 binA = scan[0];
    const u32 need1 = scan[1];

    h[threadIdx.x] = 0;
    if (threadIdx.x == 0) eqc = 0;
    __syncthreads();
    for (int i = threadIdx.x; i < n; i += 256) {
        u32 key = (u32)(cand[i] >> 32);
        if ((key >> 16) == binA) atomicAdd(&h[(key >> 8) & 0xFFu], 1u);
    }
    __syncthreads();
    if (threadIdx.x == 0) {
        u32 cum = 0; int b1 = 0;
        for (int bI = 255; bI >= 0; bI--) { if (cum + h[bI] >= need1) { b1 = bI; break; } cum += h[bI]; }
        sh_b1 = (u32)b1; sh_need2 = need1 - cum;
    }
    __syncthreads();
    u32 b1 = sh_b1, need2 = sh_need2;
    h[threadIdx.x] = 0;
    __syncthreads();
    const u32 pre24 = (binA << 8) | b1;
    for (int i = threadIdx.x; i < n; i += 256) {
        u32 key = (u32)(cand[i] >> 32);
        if ((key >> 8) == pre24) atomicAdd(&h[key & 0xFFu], 1u);
    }
    __syncthreads();
    if (threadIdx.x == 0) {
        u32 cum = 0; int b0 = 0;
        for (int bI = 255; bI >= 0; bI--) { if (cum + h[bI] >= need2) { b0 = bI; break; } cum += h[bI]; }
        sh_K = (pre24 << 8) | (u32)b0; sh_need3 = need2 - cum;
    }
    __syncthreads();
    const u32 K = sh_K, need3 = sh_need3;
    for (int i = threadIdx.x; i < n; i += 256) {
        u64 code = cand[i];
        u32 key = (u32)(code >> 32), vi = (u32)code;
        if (key > K) atomicOr(&hib[vi >> 6], 1ull << (vi & 63));
        else if (key == K) { u32 p = atomicAdd(&eqc, 1u); if (p < 2048) eqlist[p] = vi; }
    }
    __syncthreads();
    if (threadIdx.x == 0) {
        int m = (int)(eqc < 2048u ? eqc : 2048u);
        u32 prev = 0; bool first = true;
        for (u32 k = 0; k < need3; k++) {
            u32 best = 0xFFFFFFFFu;
            for (int i = 0; i < m; i++) {
                u32 x = eqlist[i];
                if ((first || x > prev) && x < best) best = x;
            }
            if (best == 0xFFFFFFFFu) break;
            atomicOr(&hib[best >> 6], 1ull << (best & 63));
            prev = best; first = false;
        }
    }
}

// ---- dilation along D for both masks ----
__global__ __launch_bounds__(256) void k_dilD(const u64* __restrict__ posb,
        const u64* __restrict__ hib, u64* __restrict__ dtmp)
{
    int t = blockIdx.x * 256 + threadIdx.x;     // 0 .. 2*NW-1
    int m = t >> 16, wI = t & 65535;
    const u64* in = m ? hib : posb;
    int dd = (wI >> 8) & 127;
    int base = wI - (dd << 8);
    int lo = dd > 10 ? dd - 10 : 0, hi2 = dd + 10 > 127 ? 127 : dd + 10;
    u64 r = 0;
    for (int j = lo; j <= hi2; j++) r |= in[base + (j << 8)];
    dtmp[t] = r;
}

// ---- dilation along H then W, per (mask, b, d) slice in LDS ----
__global__ __launch_bounds__(256) void k_dilHW(const u64* __restrict__ dtmp,
        u64* __restrict__ dilp, u64* __restrict__ dilh)
{
    __shared__ u64 A[256], Bsh[256];
    int m = blockIdx.x >> 8, s = blockIdx.x & 255;      // s = b*128 + d
    int slicebase = (m << 16) + s * 256;
    A[threadIdx.x] = dtmp[slicebase + threadIdx.x];
    __syncthreads();
    int hh = threadIdx.x >> 1, col = threadIdx.x & 1;
    int lo = hh > 10 ? hh - 10 : 0, hi2 = hh + 10 > 127 ? 127 : hh + 10;
    u64 r = 0;
    for (int j = lo; j <= hi2; j++) r |= A[(j << 1) + col];
    Bsh[threadIdx.x] = r;
    __syncthreads();
    if (threadIdx.x < 128) {
        u64 lo64 = Bsh[threadIdx.x * 2], hi64 = Bsh[threadIdx.x * 2 + 1];
        u64 rl = lo64, rh = hi64;
        #pragma unroll
        for (int sft = 1; sft <= 10; sft++) {
            rl |= (lo64 << sft) | (lo64 >> sft) | (hi64 << (64 - sft));
            rh |= (hi64 << sft) | (hi64 >> sft) | (lo64 >> (64 - sft));
        }
        u64* out = m ? dilh : dilp;
        int wbase = s * 256 + threadIdx.x * 2;
        out[wbase] = rl; out[wbase + 1] = rh;
    }
}

// ---- final masked sums over cos_map ----
__global__ __launch_bounds__(256) void k_fin(const float* __restrict__ cosm,
        const u64* __restrict__ posb, const u64* __restrict__ dilp,
        const u64* __restrict__ dilh, double* __restrict__ acc)
{
    int tid = blockIdx.x * 256 + threadIdx.x;
    const int gstride = gridDim.x * 256;
    const int lane = threadIdx.x & 63;
    float sp = 0.f, se = 0.f, sf = 0.f;
    int cE = 0, cF = 0;
    for (int idx = tid; idx < NVOX / 4; idx += gstride) {
        const int v4 = idx << 2;
        int wI = v4 >> 6, sh = v4 & 63;
        u64 pb = posb[wI];
        u32 np_ = (u32)(pb >> sh) & 0xFu;
        u32 ne  = (u32)(((dilp[wI] & ~pb) >> sh)) & 0xFu;
        u32 nf  = (u32)(((dilh[wI] & ~pb) >> sh)) & 0xFu;
        if (!(np_ | ne | nf)) continue;
        float4 cv = *(const float4*)(cosm + v4);
        const float C[4] = {cv.x, cv.y, cv.z, cv.w};
        #pragma unroll
        for (int j = 0; j < 4; j++) {
            float cs = C[j], rl = fmaxf(cs, 0.f);
            if ((np_ >> j) & 1) sp += 1.f - cs;
            if ((ne >> j) & 1) { se += rl; cE++; }
            if ((nf >> j) & 1) { sf += rl; cF++; }
        }
    }
    __shared__ double red[4][5];
    int wid = threadIdx.x >> 6;
    double vals[5] = {(double)sp, (double)se, (double)cE, (double)sf, (double)cF};
    #pragma unroll
    for (int i = 0; i < 5; i++) {
        double x = wave_red(vals[i]);
        if (lane == 0) red[wid][i] = x;
    }
    __syncthreads();
    if (threadIdx.x < 5) {
        double s = red[0][threadIdx.x] + red[1][threadIdx.x] + red[2][threadIdx.x] + red[3][threadIdx.x];
        atomicAdd(&acc[26 + threadIdx.x], s);
    }
}

// ---- combine into the scalar loss ----
__global__ void k_combine(const double* __restrict__ acc, float* __restrict__ out) {
    if (threadIdx.x != 0 || blockIdx.x != 0) return;
    double ce = acc[19] / (double)NVOX;
    double dcl = 0;
    for (int c = 1; c <= 2; c++) {
        double T = acc[23 + c], S = acc[20 + c], N = acc[16 + c];
        dcl += (2.0 * T + 1e-5) / fmax(S + N + 1e-5, 1e-8);
    }
    double dc_loss = -(dcl / 2.0);
    double cnt = acc[17];
    double pl = (cnt > 0.0) ? acc[26] / fmax(cnt, 1.0) : 0.0;
    double ml = (acc[28] > 0.0) ? acc[27] / acc[28] : 0.0;
    double nl = (acc[30] > 0.0) ? acc[29] / acc[30] : 0.0;
    out[0] = (float)(ce + dc_loss + 5.0 * (pl + ml + nl));
}

extern "C" void kernel_launch(void* const* d_in, const int* in_sizes, int n_in,
                              void* d_out, int out_size, void* d_ws, size_t ws_size,
                              hipStream_t stream)
{
    const float* feat = (const float*)d_in[0];
    const float* net  = (const float*)d_in[1];
    const int*   tgt  = (const int*)d_in[2];
    float* out = (float*)d_out;
    char* w = (char*)d_ws;

    double* acc  = (double*)(w + ACC_OFF);
    float* stdn  = (float*)(w + STD_OFF);
    u32* scan    = (u32*)(w + SCAN_OFF);
    u32* hist    = (u32*)(w + HIST_OFF);
    u64* hib     = (u64*)(w + HIB_OFF);
    u64* posb    = (u64*)(w + POSB_OFF);
    u64* negb    = (u64*)(w + NEGB_OFF);
    u64* dtmp    = (u64*)(w + DTMP_OFF);
    u64* dilp    = (u64*)(w + DILP_OFF);
    u64* dilh    = (u64*)(w + DILH_OFF);
    u64* cand    = (u64*)(w + CAND_OFF);
    float* cosm  = (float*)(w + COS_OFF);

    hipMemsetAsync(w, 0, ZERO_BYTES, stream);

    k_main   <<<2048, 256, 0, stream>>>(feat, net, tgt, posb, negb, acc);
    k_std    <<<1,    64,  0, stream>>>(acc, stdn);
    k_cos    <<<2048, 256, 0, stream>>>(feat, stdn, negb, cosm, hist);
    k_scanA  <<<1,    256, 0, stream>>>(hist, scan);
    k_collect<<<2048, 256, 0, stream>>>(cosm, negb, scan, cand);
    k_select <<<1,    256, 0, stream>>>(cand, scan, hib);
    k_dilD   <<<512,  256, 0, stream>>>(posb, hib, dtmp);
    k_dilHW  <<<512,  256, 0, stream>>>(dtmp, dilp, dilh);
    k_fin    <<<2048, 256, 0, stream>>>(cosm, posb, dilp, dilh, acc);
    k_combine<<<1,    64,  0, stream>>>(acc, out);
}

// Round 3
// 394.532 us; speedup vs baseline: 1.7989x; 1.7989x over previous
//
#include <hip/hip_runtime.h>
#include <hip/hip_bf16.h>
#include <math.h>

// Problem constants (fixed by setup_inputs)
#define S3    128
#define NB    2
#define CF    16
#define CHS   (S3*S3*S3)          // 2097152 per-channel voxels
#define NVOX  (NB*CHS)            // 4194304
#define NW    (NVOX/64)           // 65536 bit-words per mask
#define CAP   1048576             // candidate buffer entries

typedef unsigned long long u64;
typedef unsigned int u32;

// ---- workspace layout (bytes) ----
// zeroed region: acc + stdn + scan + hist(4096 bins) + hib
#define ACC_OFF    0                       // double[32]
#define STD_OFF    512                     // float[16]
#define SCAN_OFF   576                     // u32[32]
#define HIST_OFF   1024                    // u32[4096] = 16 KB
#define HIB_OFF    (HIST_OFF + 4096*4)     // u64[NW]
#define ZERO_BYTES (HIB_OFF + NW*8)
#define POSB_OFF   544768                  // 16B-aligned, > ZERO_BYTES
#define NEGB_OFF   (POSB_OFF + NW*8)
#define DTMP_OFF   (NEGB_OFF + NW*8)       // 2 masks
#define DILP_OFF   (DTMP_OFF + 2*NW*8)
#define DILH_OFF   (DILP_OFF + NW*8)
#define CAND_OFF   (DILH_OFF + NW*8)       // u64[CAP]
#define COS_OFF    (CAND_OFF + CAP*8)      // float[NVOX] (16-byte aligned)

// accumulator (doubles): 0..15 fs; 16..18 n0,n1,n2; 19 ce; 20..22 S_c; 23..25 T_c;
// 26 s_pos; 27 s_easy; 28 c_easy; 29 s_fneg; 30 c_fneg

__device__ __forceinline__ double wave_red(double x) {
    for (int o = 32; o > 0; o >>= 1) x += __shfl_down(x, o);
    return x;
}
__device__ __forceinline__ u32 mono_key(float f) {
    u32 u = __float_as_uint(f);
    return (u & 0x80000000u) ? ~u : (u | 0x80000000u);
}
// deposit 16 bits to every 4th bit position of a u64
__device__ __forceinline__ u64 spread4(u32 x16) {
    u64 x = (u64)(x16 & 0xFFFFu);
    x = (x | (x << 24)) & 0x000000FF000000FFull;
    x = (x | (x << 12)) & 0x000F000F000F000Full;
    x = (x | (x << 6))  & 0x0303030303030303ull;
    x = (x | (x << 3))  & 0x1111111111111111ull;
    return x;
}

// ---- pass 1 (fused): masks + class counts + pos-feature sums + CE/dice sums ----
__global__ __launch_bounds__(256) void k_main(const float* __restrict__ feat,
        const float* __restrict__ net, const int* __restrict__ tgt,
        u64* __restrict__ posb, u64* __restrict__ negb, double* __restrict__ acc)
{
    int tid = blockIdx.x * 256 + threadIdx.x;
    const int gstride = gridDim.x * 256;
    const int lane = threadIdx.x & 63;
    float fs[16];
    #pragma unroll
    for (int c = 0; c < 16; c++) fs[c] = 0.f;
    float ce = 0.f, s0 = 0.f, s1 = 0.f, s2 = 0.f, ta0 = 0.f, ta1 = 0.f, ta2 = 0.f;
    int n0 = 0, n1 = 0, n2 = 0;

    for (int idx = tid; idx < NVOX / 4; idx += gstride) {
        const int v4 = idx << 2;
        const int b = v4 >> 21;
        const int4 tv = *(const int4*)(tgt + v4);
        const int T[4] = {tv.x, tv.y, tv.z, tv.w};
        u32 nib_p = (u32)(T[0]==1) | ((u32)(T[1]==1)<<1) | ((u32)(T[2]==1)<<2) | ((u32)(T[3]==1)<<3);
        u32 nib_n = (u32)(T[0]==0) | ((u32)(T[1]==0)<<1) | ((u32)(T[2]==0)<<2) | ((u32)(T[3]==0)<<3);
        int pp = __popc(nib_p), nn_ = __popc(nib_n);
        n1 += pp; n0 += nn_; n2 += 4 - pp - nn_;

        // pack bitmask words (wave covers 256 consecutive voxels = 4 u64 words)
        u64 bp0 = __ballot(nib_p & 1), bp1 = __ballot(nib_p & 2),
            bp2 = __ballot(nib_p & 4), bp3 = __ballot(nib_p & 8);
        u64 bn0 = __ballot(nib_n & 1), bn1 = __ballot(nib_n & 2),
            bn2 = __ballot(nib_n & 4), bn3 = __ballot(nib_n & 8);
        if ((lane & 15) == 0) {
            int wsel = lane >> 4, sh = wsel << 4;
            u64 wp = spread4((u32)(bp0 >> sh)) | (spread4((u32)(bp1 >> sh)) << 1)
                   | (spread4((u32)(bp2 >> sh)) << 2) | (spread4((u32)(bp3 >> sh)) << 3);
            u64 wn = spread4((u32)(bn0 >> sh)) | (spread4((u32)(bn1 >> sh)) << 1)
                   | (spread4((u32)(bn2 >> sh)) << 2) | (spread4((u32)(bn3 >> sh)) << 3);
            int wi = ((idx - lane) >> 4) + wsel;
            posb[wi] = wp; negb[wi] = wn;
        }

        // CE + dice sums (3-class softmax on 4 voxels)
        const size_t nbase = (size_t)v4 + (size_t)b * (2u * CHS);
        float4 a0 = *(const float4*)(net + nbase);
        float4 a1 = *(const float4*)(net + nbase + CHS);
        float4 a2 = *(const float4*)(net + nbase + 2 * (size_t)CHS);
        const float X0[4] = {a0.x, a0.y, a0.z, a0.w};
        const float X1[4] = {a1.x, a1.y, a1.z, a1.w};
        const float X2[4] = {a2.x, a2.y, a2.z, a2.w};
        #pragma unroll
        for (int j = 0; j < 4; j++) {
            float x0 = X0[j], x1 = X1[j], x2 = X2[j];
            float m = fmaxf(x0, fmaxf(x1, x2));
            float e0 = expf(x0 - m), e1 = expf(x1 - m), e2 = expf(x2 - m);
            float sum = e0 + e1 + e2;
            float lse = m + logf(sum);
            int t = T[j];
            float xt = (t == 0) ? x0 : ((t == 1) ? x1 : x2);
            ce += lse - xt;
            float inv = 1.f / sum;
            float p0 = e0 * inv, p1 = e1 * inv, p2 = e2 * inv;
            s0 += p0; s1 += p1; s2 += p2;
            if (t == 0) ta0 += p0; else if (t == 1) ta1 += p1; else ta2 += p2;
        }

        // pos-feature channel sums (skip if no positive in this quad)
        if (nib_p) {
            const float* fb = feat + (size_t)v4 + (size_t)b * ((size_t)(CF - 1) * CHS);
            float w0 = (float)(nib_p & 1), w1 = (float)((nib_p >> 1) & 1),
                  w2 = (float)((nib_p >> 2) & 1), w3 = (float)((nib_p >> 3) & 1);
            #pragma unroll
            for (int c = 0; c < 16; c++) {
                float4 f = *(const float4*)(fb + (size_t)c * CHS);
                fs[c] += f.x * w0 + f.y * w1 + f.z * w2 + f.w * w3;
            }
        }
    }

    __shared__ double red[4][26];
    double vals[26];
    #pragma unroll
    for (int c = 0; c < 16; c++) vals[c] = (double)fs[c];
    vals[16] = n0; vals[17] = n1; vals[18] = n2;
    vals[19] = ce; vals[20] = s0; vals[21] = s1; vals[22] = s2;
    vals[23] = ta0; vals[24] = ta1; vals[25] = ta2;
    int wid = threadIdx.x >> 6;
    #pragma unroll
    for (int i = 0; i < 26; i++) {
        double x = wave_red(vals[i]);
        if (lane == 0) red[wid][i] = x;
    }
    __syncthreads();
    if (threadIdx.x < 26) {
        double s = red[0][threadIdx.x] + red[1][threadIdx.x] + red[2][threadIdx.x] + red[3][threadIdx.x];
        atomicAdd(&acc[threadIdx.x], s);
    }
}

// ---- std_n from pos-feature sums ----
__global__ void k_std(const double* __restrict__ acc, float* __restrict__ stdn) {
    __shared__ float v[16];
    double cnt = acc[17];
    if (threadIdx.x < 16) {
        double mp = acc[threadIdx.x] / fmax(cnt, 1.0);
        v[threadIdx.x] = (cnt > 0.0) ? (float)mp : 0.0f;
    }
    __syncthreads();
    if (threadIdx.x == 0) {
        float n = 0;
        for (int c = 0; c < 16; c++) n += v[c] * v[c];
        n = fmaxf(sqrtf(n), 1e-12f);
        for (int c = 0; c < 16; c++) stdn[c] = v[c] / n;
    }
}

// ---- pass 2: cos_map + per-block LDS 4096-bin histogram of negative keys ----
__global__ __launch_bounds__(256) void k_cos(const float* __restrict__ feat,
        const float* __restrict__ stdn, const u64* __restrict__ negb,
        float* __restrict__ cosm, u32* __restrict__ hist)
{
    __shared__ u32 h[4096];
    __shared__ float sn[16];
    for (int i = threadIdx.x; i < 4096; i += 256) h[i] = 0;
    if (threadIdx.x < 16) sn[threadIdx.x] = stdn[threadIdx.x];
    __syncthreads();
    int tid = blockIdx.x * 256 + threadIdx.x;
    const int gstride = gridDim.x * 256;
    for (int idx = tid; idx < NVOX / 4; idx += gstride) {
        const int v4 = idx << 2;
        const int b = v4 >> 21;
        const float* fb = feat + (size_t)v4 + (size_t)b * ((size_t)(CF - 1) * CHS);
        float d0 = 0, d1 = 0, d2 = 0, d3 = 0, q0 = 0, q1 = 0, q2 = 0, q3 = 0;
        #pragma unroll
        for (int c = 0; c < 16; c++) {
            float4 f = *(const float4*)(fb + (size_t)c * CHS);
            float s = sn[c];
            d0 = fmaf(f.x, s, d0); q0 = fmaf(f.x, f.x, q0);
            d1 = fmaf(f.y, s, d1); q1 = fmaf(f.y, f.y, q1);
            d2 = fmaf(f.z, s, d2); q2 = fmaf(f.z, f.z, q2);
            d3 = fmaf(f.w, s, d3); q3 = fmaf(f.w, f.w, q3);
        }
        float c0 = d0 / fmaxf(sqrtf(q0), 1e-12f);
        float c1 = d1 / fmaxf(sqrtf(q1), 1e-12f);
        float c2 = d2 / fmaxf(sqrtf(q2), 1e-12f);
        float c3 = d3 / fmaxf(sqrtf(q3), 1e-12f);
        *(float4*)(cosm + v4) = make_float4(c0, c1, c2, c3);
        u32 nib = (u32)(negb[v4 >> 6] >> (v4 & 63)) & 0xFu;
        if (nib & 1) atomicAdd(&h[mono_key(c0) >> 20], 1u);
        if (nib & 2) atomicAdd(&h[mono_key(c1) >> 20], 1u);
        if (nib & 4) atomicAdd(&h[mono_key(c2) >> 20], 1u);
        if (nib & 8) atomicAdd(&h[mono_key(c3) >> 20], 1u);
    }
    __syncthreads();
    for (int i = threadIdx.x; i < 4096; i += 256)
        if (h[i]) atomicAdd(&hist[i], h[i]);
}

// ---- find 12-bit bin containing the 250th key (descending) ----
__global__ void k_scanA(const u32* __restrict__ hist, u32* __restrict__ scan) {
    __shared__ u32 cs[256];
    u32 s = 0; int base = threadIdx.x * 16;
    for (int j = 0; j < 16; j++) s += hist[base + j];
    cs[threadIdx.x] = s;
    __syncthreads();
    if (threadIdx.x == 0) {
        u32 need = 250, cum = 0; int chunk = 0;
        for (int c = 255; c >= 0; c--) { if (cum + cs[c] >= need) { chunk = c; break; } cum += cs[c]; }
        int bin = chunk * 16;
        for (int bI = chunk * 16 + 15; bI >= chunk * 16; bI--) {
            if (cum + hist[bI] >= need) { bin = bI; break; }
            cum += hist[bI];
        }
        scan[0] = (u32)bin;        // binA (12-bit prefix)
        scan[1] = need - cum;      // residual need within binA
    }
}

// ---- collect candidates (neg & key >= binA<<20) ----
__global__ __launch_bounds__(256) void k_collect(const float* __restrict__ cosm,
        const u64* __restrict__ negb, u32* __restrict__ scan, u64* __restrict__ cand)
{
    const u32 thr = scan[0] << 20;
    int tid = blockIdx.x * 256 + threadIdx.x;
    const int gstride = gridDim.x * 256;
    for (int idx = tid; idx < NVOX / 4; idx += gstride) {
        const int v4 = idx << 2;
        u32 nib = (u32)(negb[v4 >> 6] >> (v4 & 63)) & 0xFu;
        if (!nib) continue;
        float4 cv = *(const float4*)(cosm + v4);
        const float C[4] = {cv.x, cv.y, cv.z, cv.w};
        #pragma unroll
        for (int j = 0; j < 4; j++) {
            if ((nib >> j) & 1) {
                u32 key = mono_key(C[j]);
                if (key >= thr) {
                    u32 p = atomicAdd(&scan[4], 1u);
                    if (p < CAP) cand[p] = ((u64)key << 32) | (u32)(v4 + j);
                }
            }
        }
    }
}

// ---- single-block exact top-250 threshold + mark hi bits ----
// binA gives key bits [31:20]; refine bits [19:8] (4096-bin LDS), then [7:0] (256-bin).
__global__ __launch_bounds__(256) void k_select(const u64* __restrict__ cand,
        const u32* __restrict__ scan, u64* __restrict__ hib)
{
    __shared__ u32 h[4096];
    __shared__ u32 eqlist[2048];
    __shared__ u32 eqc, sh_b1, sh_need2, sh_K, sh_need3;
    const u32 cnt = scan[4];
    const int n = (int)(cnt < CAP ? cnt : CAP);
    const u32 binA = scan[0];
    const u32 need1 = scan[1];

    for (int i = threadIdx.x; i < 4096; i += 256) h[i] = 0;
    if (threadIdx.x == 0) eqc = 0;
    __syncthreads();
    for (int i = threadIdx.x; i < n; i += 256) {
        u32 key = (u32)(cand[i] >> 32);
        if ((key >> 20) == binA) atomicAdd(&h[(key >> 8) & 0xFFFu], 1u);
    }
    __syncthreads();
    if (threadIdx.x == 0) {
        u32 cum = 0; int b1 = 0;
        for (int bI = 4095; bI >= 0; bI--) { if (cum + h[bI] >= need1) { b1 = bI; break; } cum += h[bI]; }
        sh_b1 = (u32)b1; sh_need2 = need1 - cum;
    }
    __syncthreads();
    u32 b1 = sh_b1, need2 = sh_need2;
    for (int i = threadIdx.x; i < 4096; i += 256) h[i] = 0;
    __syncthreads();
    const u32 pre24 = (binA << 12) | b1;      // key bits [31:8]
    for (int i = threadIdx.x; i < n; i += 256) {
        u32 key = (u32)(cand[i] >> 32);
        if ((key >> 8) == pre24) atomicAdd(&h[key & 0xFFu], 1u);
    }
    __syncthreads();
    if (threadIdx.x == 0) {
        u32 cum = 0; int b0 = 0;
        for (int bI = 255; bI >= 0; bI--) { if (cum + h[bI] >= need2) { b0 = bI; break; } cum += h[bI]; }
        sh_K = (pre24 << 8) | (u32)b0; sh_need3 = need2 - cum;
    }
    __syncthreads();
    const u32 K = sh_K, need3 = sh_need3;
    for (int i = threadIdx.x; i < n; i += 256) {
        u64 code = cand[i];
        u32 key = (u32)(code >> 32), vi = (u32)code;
        if (key > K) atomicOr(&hib[vi >> 6], 1ull << (vi & 63));
        else if (key == K) { u32 p = atomicAdd(&eqc, 1u); if (p < 2048) eqlist[p] = vi; }
    }
    __syncthreads();
    if (threadIdx.x == 0) {
        int m = (int)(eqc < 2048u ? eqc : 2048u);
        u32 prev = 0; bool first = true;
        for (u32 k = 0; k < need3; k++) {
            u32 best = 0xFFFFFFFFu;
            for (int i = 0; i < m; i++) {
                u32 x = eqlist[i];
                if ((first || x > prev) && x < best) best = x;
            }
            if (best == 0xFFFFFFFFu) break;
            atomicOr(&hib[best >> 6], 1ull << (best & 63));
            prev = best; first = false;
        }
    }
}

// ---- dilation along D for both masks ----
__global__ __launch_bounds__(256) void k_dilD(const u64* __restrict__ posb,
        const u64* __restrict__ hib, u64* __restrict__ dtmp)
{
    int t = blockIdx.x * 256 + threadIdx.x;     // 0 .. 2*NW-1
    int m = t >> 16, wI = t & 65535;
    const u64* in = m ? hib : posb;
    int dd = (wI >> 8) & 127;
    int base = wI - (dd << 8);
    int lo = dd > 10 ? dd - 10 : 0, hi2 = dd + 10 > 127 ? 127 : dd + 10;
    u64 r = 0;
    for (int j = lo; j <= hi2; j++) r |= in[base + (j << 8)];
    dtmp[t] = r;
}

// ---- dilation along H then W, per (mask, b, d) slice in LDS ----
__global__ __launch_bounds__(256) void k_dilHW(const u64* __restrict__ dtmp,
        u64* __restrict__ dilp, u64* __restrict__ dilh)
{
    __shared__ u64 A[256], Bsh[256];
    int m = blockIdx.x >> 8, s = blockIdx.x & 255;      // s = b*128 + d
    int slicebase = (m << 16) + s * 256;
    A[threadIdx.x] = dtmp[slicebase + threadIdx.x];
    __syncthreads();
    int hh = threadIdx.x >> 1, col = threadIdx.x & 1;
    int lo = hh > 10 ? hh - 10 : 0, hi2 = hh + 10 > 127 ? 127 : hh + 10;
    u64 r = 0;
    for (int j = lo; j <= hi2; j++) r |= A[(j << 1) + col];
    Bsh[threadIdx.x] = r;
    __syncthreads();
    if (threadIdx.x < 128) {
        u64 lo64 = Bsh[threadIdx.x * 2], hi64 = Bsh[threadIdx.x * 2 + 1];
        u64 rl = lo64, rh = hi64;
        #pragma unroll
        for (int sft = 1; sft <= 10; sft++) {
            rl |= (lo64 << sft) | (lo64 >> sft) | (hi64 << (64 - sft));
            rh |= (hi64 << sft) | (hi64 >> sft) | (lo64 >> (64 - sft));
        }
        u64* out = m ? dilh : dilp;
        int wbase = s * 256 + threadIdx.x * 2;
        out[wbase] = rl; out[wbase + 1] = rh;
    }
}

// ---- final masked sums over cos_map ----
__global__ __launch_bounds__(256) void k_fin(const float* __restrict__ cosm,
        const u64* __restrict__ posb, const u64* __restrict__ dilp,
        const u64* __restrict__ dilh, double* __restrict__ acc)
{
    int tid = blockIdx.x * 256 + threadIdx.x;
    const int gstride = gridDim.x * 256;
    const int lane = threadIdx.x & 63;
    float sp = 0.f, se = 0.f, sf = 0.f;
    int cE = 0, cF = 0;
    for (int idx = tid; idx < NVOX / 4; idx += gstride) {
        const int v4 = idx << 2;
        int wI = v4 >> 6, sh = v4 & 63;
        u64 pb = posb[wI];
        u32 np_ = (u32)(pb >> sh) & 0xFu;
        u32 ne  = (u32)(((dilp[wI] & ~pb) >> sh)) & 0xFu;
        u32 nf  = (u32)(((dilh[wI] & ~pb) >> sh)) & 0xFu;
        if (!(np_ | ne | nf)) continue;
        float4 cv = *(const float4*)(cosm + v4);
        const float C[4] = {cv.x, cv.y, cv.z, cv.w};
        #pragma unroll
        for (int j = 0; j < 4; j++) {
            float cs = C[j], rl = fmaxf(cs, 0.f);
            if ((np_ >> j) & 1) sp += 1.f - cs;
            if ((ne >> j) & 1) { se += rl; cE++; }
            if ((nf >> j) & 1) { sf += rl; cF++; }
        }
    }
    __shared__ double red[4][5];
    int wid = threadIdx.x >> 6;
    double vals[5] = {(double)sp, (double)se, (double)cE, (double)sf, (double)cF};
    #pragma unroll
    for (int i = 0; i < 5; i++) {
        double x = wave_red(vals[i]);
        if (lane == 0) red[wid][i] = x;
    }
    __syncthreads();
    if (threadIdx.x < 5) {
        double s = red[0][threadIdx.x] + red[1][threadIdx.x] + red[2][threadIdx.x] + red[3][threadIdx.x];
        atomicAdd(&acc[26 + threadIdx.x], s);
    }
}

// ---- combine into the scalar loss ----
__global__ void k_combine(const double* __restrict__ acc, float* __restrict__ out) {
    if (threadIdx.x != 0 || blockIdx.x != 0) return;
    double ce = acc[19] / (double)NVOX;
    double dcl = 0;
    for (int c = 1; c <= 2; c++) {
        double T = acc[23 + c], S = acc[20 + c], N = acc[16 + c];
        dcl += (2.0 * T + 1e-5) / fmax(S + N + 1e-5, 1e-8);
    }
    double dc_loss = -(dcl / 2.0);
    double cnt = acc[17];
    double pl = (cnt > 0.0) ? acc[26] / fmax(cnt, 1.0) : 0.0;
    double ml = (acc[28] > 0.0) ? acc[27] / acc[28] : 0.0;
    double nl = (acc[30] > 0.0) ? acc[29] / acc[30] : 0.0;
    out[0] = (float)(ce + dc_loss + 5.0 * (pl + ml + nl));
}

extern "C" void kernel_launch(void* const* d_in, const int* in_sizes, int n_in,
                              void* d_out, int out_size, void* d_ws, size_t ws_size,
                              hipStream_t stream)
{
    const float* feat = (const float*)d_in[0];
    const float* net  = (const float*)d_in[1];
    const int*   tgt  = (const int*)d_in[2];
    float* out = (float*)d_out;
    char* w = (char*)d_ws;

    double* acc  = (double*)(w + ACC_OFF);
    float* stdn  = (float*)(w + STD_OFF);
    u32* scan    = (u32*)(w + SCAN_OFF);
    u32* hist    = (u32*)(w + HIST_OFF);
    u64* hib     = (u64*)(w + HIB_OFF);
    u64* posb    = (u64*)(w + POSB_OFF);
    u64* negb    = (u64*)(w + NEGB_OFF);
    u64* dtmp    = (u64*)(w + DTMP_OFF);
    u64* dilp    = (u64*)(w + DILP_OFF);
    u64* dilh    = (u64*)(w + DILH_OFF);
    u64* cand    = (u64*)(w + CAND_OFF);
    float* cosm  = (float*)(w + COS_OFF);

    hipMemsetAsync(w, 0, ZERO_BYTES, stream);

    k_main   <<<2048, 256, 0, stream>>>(feat, net, tgt, posb, negb, acc);
    k_std    <<<1,    64,  0, stream>>>(acc, stdn);
    k_cos    <<<2048, 256, 0, stream>>>(feat, stdn, negb, cosm, hist);
    k_scanA  <<<1,    256, 0, stream>>>(hist, scan);
    k_collect<<<2048, 256, 0, stream>>>(cosm, negb, scan, cand);
    k_select <<<1,    256, 0, stream>>>(cand, scan, hib);
    k_dilD   <<<512,  256, 0, stream>>>(posb, hib, dtmp);
    k_dilHW  <<<512,  256, 0, stream>>>(dtmp, dilp, dilh);
    k_fin    <<<2048, 256, 0, stream>>>(cosm, posb, dilp, dilh, acc);
    k_combine<<<1,    64,  0, stream>>>(acc, out);
}

// Round 4
// 224.695 us; speedup vs baseline: 3.1585x; 1.7559x over previous
//
#include <hip/hip_runtime.h>
#include <hip/hip_bf16.h>
#include <math.h>

// Problem constants (fixed by setup_inputs)
#define S3    128
#define NB    2
#define CF    16
#define CHS   (S3*S3*S3)          // 2097152 per-channel voxels
#define NVOX  (NB*CHS)            // 4194304
#define NW    (NVOX/64)           // 65536 bit-words per mask
#define CAP   1048576             // candidate buffer entries

typedef unsigned long long u64;
typedef unsigned int u32;

// ---- workspace layout (bytes) ----
#define ACC_OFF    0                       // double[32]
#define STD_OFF    512                     // float[16]
#define SCAN_OFF   576                     // u32[32]
#define HIST_OFF   1024                    // u32[4096] = 16 KB
#define HIB_OFF    (HIST_OFF + 4096*4)     // u64[NW]
#define ZERO_BYTES (HIB_OFF + NW*8)
#define POSB_OFF   544768                  // 16B-aligned, > ZERO_BYTES
#define NEGB_OFF   (POSB_OFF + NW*8)
#define DTMP_OFF   (NEGB_OFF + NW*8)       // 2 masks
#define DILP_OFF   (DTMP_OFF + 2*NW*8)
#define DILH_OFF   (DILP_OFF + NW*8)
#define CAND_OFF   (DILH_OFF + NW*8)       // u64[CAP]
#define COS_OFF    (CAND_OFF + CAP*8)      // float[NVOX] (16-byte aligned)

// accumulator (doubles): 0..15 fs; 16..18 n0,n1,n2; 19 ce; 20..22 S_c; 23..25 T_c;
// 26 s_pos; 27 s_easy; 28 c_easy; 29 s_fneg; 30 c_fneg

__device__ __forceinline__ double wave_red(double x) {
    for (int o = 32; o > 0; o >>= 1) x += __shfl_down(x, o);
    return x;
}
__device__ __forceinline__ u32 mono_key(float f) {
    u32 u = __float_as_uint(f);
    return (u & 0x80000000u) ? ~u : (u | 0x80000000u);
}
// deposit 16 bits to every 4th bit position of a u64
__device__ __forceinline__ u64 spread4(u32 x16) {
    u64 x = (u64)(x16 & 0xFFFFu);
    x = (x | (x << 24)) & 0x000000FF000000FFull;
    x = (x | (x << 12)) & 0x000F000F000F000Full;
    x = (x | (x << 6))  & 0x0303030303030303ull;
    x = (x | (x << 3))  & 0x1111111111111111ull;
    return x;
}

// Parallel descending-bin select over NBINS LDS bins with 256 threads.
// Finds bin B s.t. (#keys in bins > B) < need <= (#keys in bins >= B).
// res[0] = B, res[1] = need - (#keys in bins > B). ss = u32[256] scratch.
template<int NBINS>
__device__ __forceinline__ void sel_desc(const u32* h, u32 need, u32* ss, u32* res)
{
    const int t = threadIdx.x;
    const int CH = NBINS / 256;
    u32 s = 0;
    #pragma unroll
    for (int j = 0; j < CH; j++) s += h[t * CH + j];
    ss[t] = s;
    __syncthreads();
    for (int o = 1; o < 256; o <<= 1) {      // inclusive suffix sum
        u32 v = (t + o < 256) ? ss[t + o] : 0;
        __syncthreads();
        ss[t] += v;
        __syncthreads();
    }
    u32 above = ss[t] - s;                   // strictly-above-chunk count
    if (above < need && above + s >= need) { // unique thread
        u32 cum = above;
        int bin = t * CH;
        for (int b = t * CH + CH - 1; b >= t * CH; b--) {
            if (cum + h[b] >= need) { bin = b; break; }
            cum += h[b];
        }
        res[0] = (u32)bin;
        res[1] = need - cum;
    }
    __syncthreads();
}

// ---- pass 1 (fused): masks + class counts + pos-feature sums + CE/dice sums ----
__global__ __launch_bounds__(256) void k_main(const float* __restrict__ feat,
        const float* __restrict__ net, const int* __restrict__ tgt,
        u64* __restrict__ posb, u64* __restrict__ negb, double* __restrict__ acc)
{
    int tid = blockIdx.x * 256 + threadIdx.x;
    const int gstride = gridDim.x * 256;
    const int lane = threadIdx.x & 63;
    float fs[16];
    #pragma unroll
    for (int c = 0; c < 16; c++) fs[c] = 0.f;
    float ce = 0.f, s0 = 0.f, s1 = 0.f, s2 = 0.f, ta0 = 0.f, ta1 = 0.f, ta2 = 0.f;
    int n0 = 0, n1 = 0, n2 = 0;

    for (int idx = tid; idx < NVOX / 4; idx += gstride) {
        const int v4 = idx << 2;
        const int b = v4 >> 21;
        const int4 tv = *(const int4*)(tgt + v4);
        const int T[4] = {tv.x, tv.y, tv.z, tv.w};
        u32 nib_p = (u32)(T[0]==1) | ((u32)(T[1]==1)<<1) | ((u32)(T[2]==1)<<2) | ((u32)(T[3]==1)<<3);
        u32 nib_n = (u32)(T[0]==0) | ((u32)(T[1]==0)<<1) | ((u32)(T[2]==0)<<2) | ((u32)(T[3]==0)<<3);
        int pp = __popc(nib_p), nn_ = __popc(nib_n);
        n1 += pp; n0 += nn_; n2 += 4 - pp - nn_;

        u64 bp0 = __ballot(nib_p & 1), bp1 = __ballot(nib_p & 2),
            bp2 = __ballot(nib_p & 4), bp3 = __ballot(nib_p & 8);
        u64 bn0 = __ballot(nib_n & 1), bn1 = __ballot(nib_n & 2),
            bn2 = __ballot(nib_n & 4), bn3 = __ballot(nib_n & 8);
        if ((lane & 15) == 0) {
            int wsel = lane >> 4, sh = wsel << 4;
            u64 wp = spread4((u32)(bp0 >> sh)) | (spread4((u32)(bp1 >> sh)) << 1)
                   | (spread4((u32)(bp2 >> sh)) << 2) | (spread4((u32)(bp3 >> sh)) << 3);
            u64 wn = spread4((u32)(bn0 >> sh)) | (spread4((u32)(bn1 >> sh)) << 1)
                   | (spread4((u32)(bn2 >> sh)) << 2) | (spread4((u32)(bn3 >> sh)) << 3);
            int wi = ((idx - lane) >> 4) + wsel;
            posb[wi] = wp; negb[wi] = wn;
        }

        const size_t nbase = (size_t)v4 + (size_t)b * (2u * CHS);
        float4 a0 = *(const float4*)(net + nbase);
        float4 a1 = *(const float4*)(net + nbase + CHS);
        float4 a2 = *(const float4*)(net + nbase + 2 * (size_t)CHS);
        const float X0[4] = {a0.x, a0.y, a0.z, a0.w};
        const float X1[4] = {a1.x, a1.y, a1.z, a1.w};
        const float X2[4] = {a2.x, a2.y, a2.z, a2.w};
        #pragma unroll
        for (int j = 0; j < 4; j++) {
            float x0 = X0[j], x1 = X1[j], x2 = X2[j];
            float m = fmaxf(x0, fmaxf(x1, x2));
            float e0 = expf(x0 - m), e1 = expf(x1 - m), e2 = expf(x2 - m);
            float sum = e0 + e1 + e2;
            float lse = m + logf(sum);
            int t = T[j];
            float xt = (t == 0) ? x0 : ((t == 1) ? x1 : x2);
            ce += lse - xt;
            float inv = 1.f / sum;
            float p0 = e0 * inv, p1 = e1 * inv, p2 = e2 * inv;
            s0 += p0; s1 += p1; s2 += p2;
            if (t == 0) ta0 += p0; else if (t == 1) ta1 += p1; else ta2 += p2;
        }

        if (nib_p) {
            const float* fb = feat + (size_t)v4 + (size_t)b * ((size_t)(CF - 1) * CHS);
            float w0 = (float)(nib_p & 1), w1 = (float)((nib_p >> 1) & 1),
                  w2 = (float)((nib_p >> 2) & 1), w3 = (float)((nib_p >> 3) & 1);
            #pragma unroll
            for (int c = 0; c < 16; c++) {
                float4 f = *(const float4*)(fb + (size_t)c * CHS);
                fs[c] += f.x * w0 + f.y * w1 + f.z * w2 + f.w * w3;
            }
        }
    }

    __shared__ double red[4][26];
    double vals[26];
    #pragma unroll
    for (int c = 0; c < 16; c++) vals[c] = (double)fs[c];
    vals[16] = n0; vals[17] = n1; vals[18] = n2;
    vals[19] = ce; vals[20] = s0; vals[21] = s1; vals[22] = s2;
    vals[23] = ta0; vals[24] = ta1; vals[25] = ta2;
    int wid = threadIdx.x >> 6;
    #pragma unroll
    for (int i = 0; i < 26; i++) {
        double x = wave_red(vals[i]);
        if (lane == 0) red[wid][i] = x;
    }
    __syncthreads();
    if (threadIdx.x < 26) {
        double s = red[0][threadIdx.x] + red[1][threadIdx.x] + red[2][threadIdx.x] + red[3][threadIdx.x];
        atomicAdd(&acc[threadIdx.x], s);
    }
}

// ---- std_n from pos-feature sums ----
__global__ void k_std(const double* __restrict__ acc, float* __restrict__ stdn) {
    __shared__ float v[16];
    double cnt = acc[17];
    if (threadIdx.x < 16) {
        double mp = acc[threadIdx.x] / fmax(cnt, 1.0);
        v[threadIdx.x] = (cnt > 0.0) ? (float)mp : 0.0f;
    }
    __syncthreads();
    if (threadIdx.x == 0) {
        float n = 0;
        for (int c = 0; c < 16; c++) n += v[c] * v[c];
        n = fmaxf(sqrtf(n), 1e-12f);
        for (int c = 0; c < 16; c++) stdn[c] = v[c] / n;
    }
}

// ---- pass 2: cos_map + per-block LDS 4096-bin histogram of negative keys ----
__global__ __launch_bounds__(256) void k_cos(const float* __restrict__ feat,
        const float* __restrict__ stdn, const u64* __restrict__ negb,
        float* __restrict__ cosm, u32* __restrict__ hist)
{
    __shared__ u32 h[4096];
    __shared__ float sn[16];
    for (int i = threadIdx.x; i < 4096; i += 256) h[i] = 0;
    if (threadIdx.x < 16) sn[threadIdx.x] = stdn[threadIdx.x];
    __syncthreads();
    int tid = blockIdx.x * 256 + threadIdx.x;
    const int gstride = gridDim.x * 256;
    for (int idx = tid; idx < NVOX / 4; idx += gstride) {
        const int v4 = idx << 2;
        const int b = v4 >> 21;
        const float* fb = feat + (size_t)v4 + (size_t)b * ((size_t)(CF - 1) * CHS);
        float d0 = 0, d1 = 0, d2 = 0, d3 = 0, q0 = 0, q1 = 0, q2 = 0, q3 = 0;
        #pragma unroll
        for (int c = 0; c < 16; c++) {
            float4 f = *(const float4*)(fb + (size_t)c * CHS);
            float s = sn[c];
            d0 = fmaf(f.x, s, d0); q0 = fmaf(f.x, f.x, q0);
            d1 = fmaf(f.y, s, d1); q1 = fmaf(f.y, f.y, q1);
            d2 = fmaf(f.z, s, d2); q2 = fmaf(f.z, f.z, q2);
            d3 = fmaf(f.w, s, d3); q3 = fmaf(f.w, f.w, q3);
        }
        float c0 = d0 / fmaxf(sqrtf(q0), 1e-12f);
        float c1 = d1 / fmaxf(sqrtf(q1), 1e-12f);
        float c2 = d2 / fmaxf(sqrtf(q2), 1e-12f);
        float c3 = d3 / fmaxf(sqrtf(q3), 1e-12f);
        *(float4*)(cosm + v4) = make_float4(c0, c1, c2, c3);
        u32 nib = (u32)(negb[v4 >> 6] >> (v4 & 63)) & 0xFu;
        if (nib & 1) atomicAdd(&h[mono_key(c0) >> 20], 1u);
        if (nib & 2) atomicAdd(&h[mono_key(c1) >> 20], 1u);
        if (nib & 4) atomicAdd(&h[mono_key(c2) >> 20], 1u);
        if (nib & 8) atomicAdd(&h[mono_key(c3) >> 20], 1u);
    }
    __syncthreads();
    for (int i = threadIdx.x; i < 4096; i += 256)
        if (h[i]) atomicAdd(&hist[i], h[i]);
}

// ---- find 12-bit bin containing the 250th key (descending, parallel) ----
__global__ __launch_bounds__(256) void k_scanA(const u32* __restrict__ hist, u32* __restrict__ scan) {
    __shared__ u32 h[4096];
    __shared__ u32 ss[256];
    __shared__ u32 res[2];
    for (int i = threadIdx.x; i < 4096; i += 256) h[i] = hist[i];
    __syncthreads();
    sel_desc<4096>(h, 250u, ss, res);
    if (threadIdx.x == 0) { scan[0] = res[0]; scan[1] = res[1]; }
}

// ---- collect candidates (neg & key >= binA<<20) ----
__global__ __launch_bounds__(256) void k_collect(const float* __restrict__ cosm,
        const u64* __restrict__ negb, u32* __restrict__ scan, u64* __restrict__ cand)
{
    const u32 thr = scan[0] << 20;
    int tid = blockIdx.x * 256 + threadIdx.x;
    const int gstride = gridDim.x * 256;
    for (int idx = tid; idx < NVOX / 4; idx += gstride) {
        const int v4 = idx << 2;
        u32 nib = (u32)(negb[v4 >> 6] >> (v4 & 63)) & 0xFu;
        if (!nib) continue;
        float4 cv = *(const float4*)(cosm + v4);
        const float C[4] = {cv.x, cv.y, cv.z, cv.w};
        #pragma unroll
        for (int j = 0; j < 4; j++) {
            if ((nib >> j) & 1) {
                u32 key = mono_key(C[j]);
                if (key >= thr) {
                    u32 p = atomicAdd(&scan[4], 1u);
                    if (p < CAP) cand[p] = ((u64)key << 32) | (u32)(v4 + j);
                }
            }
        }
    }
}

// ---- single-block exact top-250 threshold + mark hi bits (parallel selects) ----
__global__ __launch_bounds__(256) void k_select(const u64* __restrict__ cand,
        const u32* __restrict__ scan, u64* __restrict__ hib)
{
    __shared__ u32 h[4096];
    __shared__ u32 ss[256];
    __shared__ u32 res[2];
    __shared__ u32 eqlist[2048];
    __shared__ u32 eqc;
    const u32 cnt = scan[4];
    const int n = (int)(cnt < CAP ? cnt : CAP);
    const u32 binA = scan[0];
    const u32 need1 = scan[1];

    // phase A: histogram key bits [19:8] within binA
    for (int i = threadIdx.x; i < 4096; i += 256) h[i] = 0;
    if (threadIdx.x == 0) eqc = 0;
    __syncthreads();
    for (int i = threadIdx.x; i < n; i += 256) {
        u32 key = (u32)(cand[i] >> 32);
        if ((key >> 20) == binA) atomicAdd(&h[(key >> 8) & 0xFFFu], 1u);
    }
    __syncthreads();
    sel_desc<4096>(h, need1, ss, res);
    const u32 b1 = res[0], need2 = res[1];

    // phase B: histogram key bits [7:0] within prefix24
    for (int i = threadIdx.x; i < 4096; i += 256) h[i] = 0;
    __syncthreads();
    const u32 pre24 = (binA << 12) | b1;
    for (int i = threadIdx.x; i < n; i += 256) {
        u32 key = (u32)(cand[i] >> 32);
        if ((key >> 8) == pre24) atomicAdd(&h[key & 0xFFu], 1u);
    }
    __syncthreads();
    sel_desc<256>(h, need2, ss, res);
    const u32 K = (pre24 << 8) | res[0];
    const u32 need3 = res[1];

    // phase C: mark > K; collect == K for tie-break
    for (int i = threadIdx.x; i < n; i += 256) {
        u64 code = cand[i];
        u32 key = (u32)(code >> 32), vi = (u32)code;
        if (key > K) atomicOr(&hib[vi >> 6], 1ull << (vi & 63));
        else if (key == K) { u32 p = atomicAdd(&eqc, 1u); if (p < 2048) eqlist[p] = vi; }
    }
    __syncthreads();
    if (threadIdx.x == 0) {
        int m = (int)(eqc < 2048u ? eqc : 2048u);
        u32 prev = 0; bool first = true;
        for (u32 k = 0; k < need3; k++) {
            u32 best = 0xFFFFFFFFu;
            for (int i = 0; i < m; i++) {
                u32 x = eqlist[i];
                if ((first || x > prev) && x < best) best = x;
            }
            if (best == 0xFFFFFFFFu) break;
            atomicOr(&hib[best >> 6], 1ull << (best & 63));
            prev = best; first = false;
        }
    }
}

// ---- dilation along D for both masks ----
__global__ __launch_bounds__(256) void k_dilD(const u64* __restrict__ posb,
        const u64* __restrict__ hib, u64* __restrict__ dtmp)
{
    int t = blockIdx.x * 256 + threadIdx.x;     // 0 .. 2*NW-1
    int m = t >> 16, wI = t & 65535;
    const u64* in = m ? hib : posb;
    int dd = (wI >> 8) & 127;
    int base = wI - (dd << 8);
    int lo = dd > 10 ? dd - 10 : 0, hi2 = dd + 10 > 127 ? 127 : dd + 10;
    u64 r = 0;
    for (int j = lo; j <= hi2; j++) r |= in[base + (j << 8)];
    dtmp[t] = r;
}

// ---- dilation along H then W, per (mask, b, d) slice in LDS ----
__global__ __launch_bounds__(256) void k_dilHW(const u64* __restrict__ dtmp,
        u64* __restrict__ dilp, u64* __restrict__ dilh)
{
    __shared__ u64 A[256], Bsh[256];
    int m = blockIdx.x >> 8, s = blockIdx.x & 255;      // s = b*128 + d
    int slicebase = (m << 16) + s * 256;
    A[threadIdx.x] = dtmp[slicebase + threadIdx.x];
    __syncthreads();
    int hh = threadIdx.x >> 1, col = threadIdx.x & 1;
    int lo = hh > 10 ? hh - 10 : 0, hi2 = hh + 10 > 127 ? 127 : hh + 10;
    u64 r = 0;
    for (int j = lo; j <= hi2; j++) r |= A[(j << 1) + col];
    Bsh[threadIdx.x] = r;
    __syncthreads();
    if (threadIdx.x < 128) {
        u64 lo64 = Bsh[threadIdx.x * 2], hi64 = Bsh[threadIdx.x * 2 + 1];
        u64 rl = lo64, rh = hi64;
        #pragma unroll
        for (int sft = 1; sft <= 10; sft++) {
            rl |= (lo64 << sft) | (lo64 >> sft) | (hi64 << (64 - sft));
            rh |= (hi64 << sft) | (hi64 >> sft) | (lo64 >> (64 - sft));
        }
        u64* out = m ? dilh : dilp;
        int wbase = s * 256 + threadIdx.x * 2;
        out[wbase] = rl; out[wbase + 1] = rh;
    }
}

// ---- final masked sums over cos_map ----
__global__ __launch_bounds__(256) void k_fin(const float* __restrict__ cosm,
        const u64* __restrict__ posb, const u64* __restrict__ dilp,
        const u64* __restrict__ dilh, double* __restrict__ acc)
{
    int tid = blockIdx.x * 256 + threadIdx.x;
    const int gstride = gridDim.x * 256;
    const int lane = threadIdx.x & 63;
    float sp = 0.f, se = 0.f, sf = 0.f;
    int cE = 0, cF = 0;
    for (int idx = tid; idx < NVOX / 4; idx += gstride) {
        const int v4 = idx << 2;
        int wI = v4 >> 6, sh = v4 & 63;
        u64 pb = posb[wI];
        u32 np_ = (u32)(pb >> sh) & 0xFu;
        u32 ne  = (u32)(((dilp[wI] & ~pb) >> sh)) & 0xFu;
        u32 nf  = (u32)(((dilh[wI] & ~pb) >> sh)) & 0xFu;
        if (!(np_ | ne | nf)) continue;
        float4 cv = *(const float4*)(cosm + v4);
        const float C[4] = {cv.x, cv.y, cv.z, cv.w};
        #pragma unroll
        for (int j = 0; j < 4; j++) {
            float cs = C[j], rl = fmaxf(cs, 0.f);
            if ((np_ >> j) & 1) sp += 1.f - cs;
            if ((ne >> j) & 1) { se += rl; cE++; }
            if ((nf >> j) & 1) { sf += rl; cF++; }
        }
    }
    __shared__ double red[4][5];
    int wid = threadIdx.x >> 6;
    double vals[5] = {(double)sp, (double)se, (double)cE, (double)sf, (double)cF};
    #pragma unroll
    for (int i = 0; i < 5; i++) {
        double x = wave_red(vals[i]);
        if (lane == 0) red[wid][i] = x;
    }
    __syncthreads();
    if (threadIdx.x < 5) {
        double s = red[0][threadIdx.x] + red[1][threadIdx.x] + red[2][threadIdx.x] + red[3][threadIdx.x];
        atomicAdd(&acc[26 + threadIdx.x], s);
    }
}

// ---- combine into the scalar loss ----
__global__ void k_combine(const double* __restrict__ acc, float* __restrict__ out) {
    if (threadIdx.x != 0 || blockIdx.x != 0) return;
    double ce = acc[19] / (double)NVOX;
    double dcl = 0;
    for (int c = 1; c <= 2; c++) {
        double T = acc[23 + c], S = acc[20 + c], N = acc[16 + c];
        dcl += (2.0 * T + 1e-5) / fmax(S + N + 1e-5, 1e-8);
    }
    double dc_loss = -(dcl / 2.0);
    double cnt = acc[17];
    double pl = (cnt > 0.0) ? acc[26] / fmax(cnt, 1.0) : 0.0;
    double ml = (acc[28] > 0.0) ? acc[27] / acc[28] : 0.0;
    double nl = (acc[30] > 0.0) ? acc[29] / acc[30] : 0.0;
    out[0] = (float)(ce + dc_loss + 5.0 * (pl + ml + nl));
}

extern "C" void kernel_launch(void* const* d_in, const int* in_sizes, int n_in,
                              void* d_out, int out_size, void* d_ws, size_t ws_size,
                              hipStream_t stream)
{
    const float* feat = (const float*)d_in[0];
    const float* net  = (const float*)d_in[1];
    const int*   tgt  = (const int*)d_in[2];
    float* out = (float*)d_out;
    char* w = (char*)d_ws;

    double* acc  = (double*)(w + ACC_OFF);
    float* stdn  = (float*)(w + STD_OFF);
    u32* scan    = (u32*)(w + SCAN_OFF);
    u32* hist    = (u32*)(w + HIST_OFF);
    u64* hib     = (u64*)(w + HIB_OFF);
    u64* posb    = (u64*)(w + POSB_OFF);
    u64* negb    = (u64*)(w + NEGB_OFF);
    u64* dtmp    = (u64*)(w + DTMP_OFF);
    u64* dilp    = (u64*)(w + DILP_OFF);
    u64* dilh    = (u64*)(w + DILH_OFF);
    u64* cand    = (u64*)(w + CAND_OFF);
    float* cosm  = (float*)(w + COS_OFF);

    hipMemsetAsync(w, 0, ZERO_BYTES, stream);

    k_main   <<<2048, 256, 0, stream>>>(feat, net, tgt, posb, negb, acc);
    k_std    <<<1,    64,  0, stream>>>(acc, stdn);
    k_cos    <<<2048, 256, 0, stream>>>(feat, stdn, negb, cosm, hist);
    k_scanA  <<<1,    256, 0, stream>>>(hist, scan);
    k_collect<<<2048, 256, 0, stream>>>(cosm, negb, scan, cand);
    k_select <<<1,    256, 0, stream>>>(cand, scan, hib);
    k_dilD   <<<512,  256, 0, stream>>>(posb, hib, dtmp);
    k_dilHW  <<<512,  256, 0, stream>>>(dtmp, dilp, dilh);
    k_fin    <<<2048, 256, 0, stream>>>(cosm, posb, dilp, dilh, acc);
    k_combine<<<1,    64,  0, stream>>>(acc, out);
}

// Round 5
// 197.637 us; speedup vs baseline: 3.5910x; 1.1369x over previous
//
#include <hip/hip_runtime.h>
#include <hip/hip_bf16.h>
#include <math.h>

// Problem constants (fixed by setup_inputs)
#define S3    128
#define NB    2
#define CF    16
#define CHS   (S3*S3*S3)          // 2097152 per-channel voxels
#define NVOX  (NB*CHS)            // 4194304
#define NW    (NVOX/64)           // 65536 bit-words per mask
#define CAP   1048576             // candidate buffer entries

typedef unsigned long long u64;
typedef unsigned int u32;
typedef float f4 __attribute__((ext_vector_type(4)));
typedef int   i4 __attribute__((ext_vector_type(4)));

// ---- workspace layout (bytes) ----
#define ACC_OFF    0                       // double[32]
#define STD_OFF    512                     // float[16]
#define SCAN_OFF   576                     // u32[32]
#define HIST_OFF   1024                    // u32[4096] = 16 KB
#define HIB_OFF    (HIST_OFF + 4096*4)     // u64[NW]
#define ZERO_BYTES (HIB_OFF + NW*8)        // 541696
#define POSB_OFF   544768                  // 16B-aligned, > ZERO_BYTES
#define NEGB_OFF   (POSB_OFF + NW*8)
#define DTMP_OFF   (NEGB_OFF + NW*8)       // 2 masks (D-dilated)
#define CAND_OFF   (DTMP_OFF + 2*NW*8)     // u64[CAP]
#define COS_OFF    (CAND_OFF + CAP*8)      // float[NVOX] = 16.8 MB

// accumulator (doubles): 0..15 fs; 16..18 n0,n1,n2; 19 ce; 20..22 S_c; 23..25 T_c;
// 26 s_pos; 27 s_easy; 28 c_easy; 29 s_fneg; 30 c_fneg

__device__ __forceinline__ double wave_red(double x) {
    for (int o = 32; o > 0; o >>= 1) x += __shfl_down(x, o);
    return x;
}
__device__ __forceinline__ u32 mono_key(float f) {
    u32 u = __float_as_uint(f);
    return (u & 0x80000000u) ? ~u : (u | 0x80000000u);
}
// deposit 16 bits to every 4th bit position of a u64
__device__ __forceinline__ u64 spread4(u32 x16) {
    u64 x = (u64)(x16 & 0xFFFFu);
    x = (x | (x << 24)) & 0x000000FF000000FFull;
    x = (x | (x << 12)) & 0x000F000F000F000Full;
    x = (x | (x << 6))  & 0x0303030303030303ull;
    x = (x | (x << 3))  & 0x1111111111111111ull;
    return x;
}

// Parallel descending-bin select over NBINS LDS bins with 256 threads.
template<int NBINS>
__device__ __forceinline__ void sel_desc(const u32* h, u32 need, u32* ss, u32* res)
{
    const int t = threadIdx.x;
    const int CH = NBINS / 256;
    u32 s = 0;
    #pragma unroll
    for (int j = 0; j < CH; j++) s += h[t * CH + j];
    ss[t] = s;
    __syncthreads();
    for (int o = 1; o < 256; o <<= 1) {      // inclusive suffix sum
        u32 v = (t + o < 256) ? ss[t + o] : 0;
        __syncthreads();
        ss[t] += v;
        __syncthreads();
    }
    u32 above = ss[t] - s;                   // strictly-above-chunk count
    if (above < need && above + s >= need) { // unique thread
        u32 cum = above;
        int bin = t * CH;
        for (int b = t * CH + CH - 1; b >= t * CH; b--) {
            if (cum + h[b] >= need) { bin = b; break; }
            cum += h[b];
        }
        res[0] = (u32)bin;
        res[1] = need - cum;
    }
    __syncthreads();
}

// ---- pass 1 (fused): masks + class counts + pos-feature sums + CE/dice sums ----
// net/tgt loads are non-temporal: never reused; keep feature resident in L3 for pass 2.
__global__ __launch_bounds__(256) void k_main(const float* __restrict__ feat,
        const float* __restrict__ net, const int* __restrict__ tgt,
        u64* __restrict__ posb, u64* __restrict__ negb, double* __restrict__ acc)
{
    int tid = blockIdx.x * 256 + threadIdx.x;
    const int gstride = gridDim.x * 256;
    const int lane = threadIdx.x & 63;
    float fs[16];
    #pragma unroll
    for (int c = 0; c < 16; c++) fs[c] = 0.f;
    float ce = 0.f, s0 = 0.f, s1 = 0.f, s2 = 0.f, ta0 = 0.f, ta1 = 0.f, ta2 = 0.f;
    int n0 = 0, n1 = 0, n2 = 0;

    for (int idx = tid; idx < NVOX / 4; idx += gstride) {
        const int v4 = idx << 2;
        const int b = v4 >> 21;
        const i4 tv = __builtin_nontemporal_load((const i4*)(tgt + v4));
        const int T[4] = {tv[0], tv[1], tv[2], tv[3]};
        u32 nib_p = (u32)(T[0]==1) | ((u32)(T[1]==1)<<1) | ((u32)(T[2]==1)<<2) | ((u32)(T[3]==1)<<3);
        u32 nib_n = (u32)(T[0]==0) | ((u32)(T[1]==0)<<1) | ((u32)(T[2]==0)<<2) | ((u32)(T[3]==0)<<3);
        int pp = __popc(nib_p), nn_ = __popc(nib_n);
        n1 += pp; n0 += nn_; n2 += 4 - pp - nn_;

        u64 bp0 = __ballot(nib_p & 1), bp1 = __ballot(nib_p & 2),
            bp2 = __ballot(nib_p & 4), bp3 = __ballot(nib_p & 8);
        u64 bn0 = __ballot(nib_n & 1), bn1 = __ballot(nib_n & 2),
            bn2 = __ballot(nib_n & 4), bn3 = __ballot(nib_n & 8);
        if ((lane & 15) == 0) {
            int wsel = lane >> 4, sh = wsel << 4;
            u64 wp = spread4((u32)(bp0 >> sh)) | (spread4((u32)(bp1 >> sh)) << 1)
                   | (spread4((u32)(bp2 >> sh)) << 2) | (spread4((u32)(bp3 >> sh)) << 3);
            u64 wn = spread4((u32)(bn0 >> sh)) | (spread4((u32)(bn1 >> sh)) << 1)
                   | (spread4((u32)(bn2 >> sh)) << 2) | (spread4((u32)(bn3 >> sh)) << 3);
            int wi = ((idx - lane) >> 4) + wsel;
            posb[wi] = wp; negb[wi] = wn;
        }

        const size_t nbase = (size_t)v4 + (size_t)b * (2u * CHS);
        f4 a0 = __builtin_nontemporal_load((const f4*)(net + nbase));
        f4 a1 = __builtin_nontemporal_load((const f4*)(net + nbase + CHS));
        f4 a2 = __builtin_nontemporal_load((const f4*)(net + nbase + 2 * (size_t)CHS));
        #pragma unroll
        for (int j = 0; j < 4; j++) {
            float x0 = a0[j], x1 = a1[j], x2 = a2[j];
            float m = fmaxf(x0, fmaxf(x1, x2));
            float e0 = expf(x0 - m), e1 = expf(x1 - m), e2 = expf(x2 - m);
            float sum = e0 + e1 + e2;
            float lse = m + logf(sum);
            int t = T[j];
            float xt = (t == 0) ? x0 : ((t == 1) ? x1 : x2);
            ce += lse - xt;
            float inv = 1.f / sum;
            float p0 = e0 * inv, p1 = e1 * inv, p2 = e2 * inv;
            s0 += p0; s1 += p1; s2 += p2;
            if (t == 0) ta0 += p0; else if (t == 1) ta1 += p1; else ta2 += p2;
        }

        if (nib_p) {
            const float* fb = feat + (size_t)v4 + (size_t)b * ((size_t)(CF - 1) * CHS);
            float w0 = (float)(nib_p & 1), w1 = (float)((nib_p >> 1) & 1),
                  w2 = (float)((nib_p >> 2) & 1), w3 = (float)((nib_p >> 3) & 1);
            #pragma unroll
            for (int c = 0; c < 16; c++) {
                float4 f = *(const float4*)(fb + (size_t)c * CHS);
                fs[c] += f.x * w0 + f.y * w1 + f.z * w2 + f.w * w3;
            }
        }
    }

    __shared__ double red[4][26];
    double vals[26];
    #pragma unroll
    for (int c = 0; c < 16; c++) vals[c] = (double)fs[c];
    vals[16] = n0; vals[17] = n1; vals[18] = n2;
    vals[19] = ce; vals[20] = s0; vals[21] = s1; vals[22] = s2;
    vals[23] = ta0; vals[24] = ta1; vals[25] = ta2;
    int wid = threadIdx.x >> 6;
    #pragma unroll
    for (int i = 0; i < 26; i++) {
        double x = wave_red(vals[i]);
        if (lane == 0) red[wid][i] = x;
    }
    __syncthreads();
    if (threadIdx.x < 26) {
        double s = red[0][threadIdx.x] + red[1][threadIdx.x] + red[2][threadIdx.x] + red[3][threadIdx.x];
        atomicAdd(&acc[threadIdx.x], s);
    }
}

// ---- std_n from pos-feature sums ----
__global__ void k_std(const double* __restrict__ acc, float* __restrict__ stdn) {
    __shared__ float v[16];
    double cnt = acc[17];
    if (threadIdx.x < 16) {
        double mp = acc[threadIdx.x] / fmax(cnt, 1.0);
        v[threadIdx.x] = (cnt > 0.0) ? (float)mp : 0.0f;
    }
    __syncthreads();
    if (threadIdx.x == 0) {
        float n = 0;
        for (int c = 0; c < 16; c++) n += v[c] * v[c];
        n = fmaxf(sqrtf(n), 1e-12f);
        for (int c = 0; c < 16; c++) stdn[c] = v[c] / n;
    }
}

// ---- pass 2: cos_map + per-block LDS 4096-bin histogram of negative keys ----
// cosm stores are non-temporal (streaming) to avoid evicting feature from L3.
__global__ __launch_bounds__(256) void k_cos(const float* __restrict__ feat,
        const float* __restrict__ stdn, const u64* __restrict__ negb,
        float* __restrict__ cosm, u32* __restrict__ hist)
{
    __shared__ u32 h[4096];
    __shared__ float sn[16];
    for (int i = threadIdx.x; i < 4096; i += 256) h[i] = 0;
    if (threadIdx.x < 16) sn[threadIdx.x] = stdn[threadIdx.x];
    __syncthreads();
    int tid = blockIdx.x * 256 + threadIdx.x;
    const int gstride = gridDim.x * 256;
    for (int idx = tid; idx < NVOX / 4; idx += gstride) {
        const int v4 = idx << 2;
        const int b = v4 >> 21;
        const float* fb = feat + (size_t)v4 + (size_t)b * ((size_t)(CF - 1) * CHS);
        float d0 = 0, d1 = 0, d2 = 0, d3 = 0, q0 = 0, q1 = 0, q2 = 0, q3 = 0;
        #pragma unroll
        for (int c = 0; c < 16; c++) {
            float4 f = *(const float4*)(fb + (size_t)c * CHS);
            float s = sn[c];
            d0 = fmaf(f.x, s, d0); q0 = fmaf(f.x, f.x, q0);
            d1 = fmaf(f.y, s, d1); q1 = fmaf(f.y, f.y, q1);
            d2 = fmaf(f.z, s, d2); q2 = fmaf(f.z, f.z, q2);
            d3 = fmaf(f.w, s, d3); q3 = fmaf(f.w, f.w, q3);
        }
        f4 cv;
        cv[0] = d0 / fmaxf(sqrtf(q0), 1e-12f);
        cv[1] = d1 / fmaxf(sqrtf(q1), 1e-12f);
        cv[2] = d2 / fmaxf(sqrtf(q2), 1e-12f);
        cv[3] = d3 / fmaxf(sqrtf(q3), 1e-12f);
        __builtin_nontemporal_store(cv, (f4*)(cosm + v4));
        u32 nib = (u32)(negb[v4 >> 6] >> (v4 & 63)) & 0xFu;
        if (nib & 1) atomicAdd(&h[mono_key(cv[0]) >> 20], 1u);
        if (nib & 2) atomicAdd(&h[mono_key(cv[1]) >> 20], 1u);
        if (nib & 4) atomicAdd(&h[mono_key(cv[2]) >> 20], 1u);
        if (nib & 8) atomicAdd(&h[mono_key(cv[3]) >> 20], 1u);
    }
    __syncthreads();
    for (int i = threadIdx.x; i < 4096; i += 256)
        if (h[i]) atomicAdd(&hist[i], h[i]);
}

// ---- find 12-bit bin containing the 250th key (descending, parallel) ----
__global__ __launch_bounds__(256) void k_scanA(const u32* __restrict__ hist, u32* __restrict__ scan) {
    __shared__ u32 h[4096];
    __shared__ u32 ss[256];
    __shared__ u32 res[2];
    for (int i = threadIdx.x; i < 4096; i += 256) h[i] = hist[i];
    __syncthreads();
    sel_desc<4096>(h, 250u, ss, res);
    if (threadIdx.x == 0) { scan[0] = res[0]; scan[1] = res[1]; }
}

// ---- collect candidates (neg & key >= binA<<20) ----
__global__ __launch_bounds__(256) void k_collect(const float* __restrict__ cosm,
        const u64* __restrict__ negb, u32* __restrict__ scan, u64* __restrict__ cand)
{
    const u32 thr = scan[0] << 20;
    int tid = blockIdx.x * 256 + threadIdx.x;
    const int gstride = gridDim.x * 256;
    for (int idx = tid; idx < NVOX / 4; idx += gstride) {
        const int v4 = idx << 2;
        u32 nib = (u32)(negb[v4 >> 6] >> (v4 & 63)) & 0xFu;
        if (!nib) continue;
        float4 cv = *(const float4*)(cosm + v4);
        const float C[4] = {cv.x, cv.y, cv.z, cv.w};
        #pragma unroll
        for (int j = 0; j < 4; j++) {
            if ((nib >> j) & 1) {
                u32 key = mono_key(C[j]);
                if (key >= thr) {
                    u32 p = atomicAdd(&scan[4], 1u);
                    if (p < CAP) cand[p] = ((u64)key << 32) | (u32)(v4 + j);
                }
            }
        }
    }
}

// ---- single-block exact top-250 threshold + mark hi bits (parallel selects) ----
__global__ __launch_bounds__(256) void k_select(const u64* __restrict__ cand,
        const u32* __restrict__ scan, u64* __restrict__ hib)
{
    __shared__ u32 h[4096];
    __shared__ u32 ss[256];
    __shared__ u32 res[2];
    __shared__ u32 eqlist[2048];
    __shared__ u32 eqc;
    const u32 cnt = scan[4];
    const int n = (int)(cnt < CAP ? cnt : CAP);
    const u32 binA = scan[0];
    const u32 need1 = scan[1];

    for (int i = threadIdx.x; i < 4096; i += 256) h[i] = 0;
    if (threadIdx.x == 0) eqc = 0;
    __syncthreads();
    for (int i = threadIdx.x; i < n; i += 256) {
        u32 key = (u32)(cand[i] >> 32);
        if ((key >> 20) == binA) atomicAdd(&h[(key >> 8) & 0xFFFu], 1u);
    }
    __syncthreads();
    sel_desc<4096>(h, need1, ss, res);
    const u32 b1 = res[0], need2 = res[1];

    for (int i = threadIdx.x; i < 4096; i += 256) h[i] = 0;
    __syncthreads();
    const u32 pre24 = (binA << 12) | b1;
    for (int i = threadIdx.x; i < n; i += 256) {
        u32 key = (u32)(cand[i] >> 32);
        if ((key >> 8) == pre24) atomicAdd(&h[key & 0xFFu], 1u);
    }
    __syncthreads();
    sel_desc<256>(h, need2, ss, res);
    const u32 K = (pre24 << 8) | res[0];
    const u32 need3 = res[1];

    for (int i = threadIdx.x; i < n; i += 256) {
        u64 code = cand[i];
        u32 key = (u32)(code >> 32), vi = (u32)code;
        if (key > K) atomicOr(&hib[vi >> 6], 1ull << (vi & 63));
        else if (key == K) { u32 p = atomicAdd(&eqc, 1u); if (p < 2048) eqlist[p] = vi; }
    }
    __syncthreads();
    if (threadIdx.x == 0) {
        int m = (int)(eqc < 2048u ? eqc : 2048u);
        u32 prev = 0; bool first = true;
        for (u32 k = 0; k < need3; k++) {
            u32 best = 0xFFFFFFFFu;
            for (int i = 0; i < m; i++) {
                u32 x = eqlist[i];
                if ((first || x > prev) && x < best) best = x;
            }
            if (best == 0xFFFFFFFFu) break;
            atomicOr(&hib[best >> 6], 1ull << (best & 63));
            prev = best; first = false;
        }
    }
}

// ---- dilation along D for both masks ----
__global__ __launch_bounds__(256) void k_dilD(const u64* __restrict__ posb,
        const u64* __restrict__ hib, u64* __restrict__ dtmp)
{
    int t = blockIdx.x * 256 + threadIdx.x;     // 0 .. 2*NW-1
    int m = t >> 16, wI = t & 65535;
    const u64* in = m ? hib : posb;
    int dd = (wI >> 8) & 127;
    int base = wI - (dd << 8);
    int lo = dd > 10 ? dd - 10 : 0, hi2 = dd + 10 > 127 ? 127 : dd + 10;
    u64 r = 0;
    for (int j = lo; j <= hi2; j++) r |= in[base + (j << 8)];
    dtmp[t] = r;
}

// ---- fused: H+W dilation of both masks per (b,d) slice + final masked sums ----
__global__ __launch_bounds__(256) void k_dilfin(const u64* __restrict__ dtmp,
        const u64* __restrict__ posb, const float* __restrict__ cosm,
        double* __restrict__ acc)
{
    __shared__ u64 A0[256], A1[256], B0[256], B1[256], E[256], F[256], P[256];
    __shared__ double red[4][5];
    const int s = blockIdx.x;            // slice = b*128 + d
    const int t = threadIdx.x;
    const int sbase = s * 256;
    A0[t] = dtmp[sbase + t];
    A1[t] = dtmp[65536 + sbase + t];
    P[t]  = posb[sbase + t];
    __syncthreads();
    // H dilation (word j: h=j>>1, col=j&1)
    {
        int hh = t >> 1, col = t & 1;
        int lo = hh > 10 ? hh - 10 : 0, hi2 = hh + 10 > 127 ? 127 : hh + 10;
        u64 r0 = 0, r1 = 0;
        for (int j = lo; j <= hi2; j++) { r0 |= A0[(j << 1) + col]; r1 |= A1[(j << 1) + col]; }
        B0[t] = r0; B1[t] = r1;
    }
    __syncthreads();
    // W dilation (rows h = 0..127, 128-bit smear)
    if (t < 128) {
        u64 lo0 = B0[t * 2], hi0 = B0[t * 2 + 1];
        u64 lo1 = B1[t * 2], hi1 = B1[t * 2 + 1];
        u64 rl0 = lo0, rh0 = hi0, rl1 = lo1, rh1 = hi1;
        #pragma unroll
        for (int sft = 1; sft <= 10; sft++) {
            rl0 |= (lo0 << sft) | (lo0 >> sft) | (hi0 << (64 - sft));
            rh0 |= (hi0 << sft) | (hi0 >> sft) | (lo0 >> (64 - sft));
            rl1 |= (lo1 << sft) | (lo1 >> sft) | (hi1 << (64 - sft));
            rh1 |= (hi1 << sft) | (hi1 >> sft) | (lo1 >> (64 - sft));
        }
        E[t * 2] = rl0; E[t * 2 + 1] = rh0;
        F[t * 2] = rl1; F[t * 2 + 1] = rh1;
    }
    __syncthreads();
    // masked sums over this slice's cos values (16384 voxels)
    float sp = 0.f, se = 0.f, sf = 0.f;
    int cE = 0, cF = 0;
    const float* cbase = cosm + (size_t)s * 16384;
    #pragma unroll 4
    for (int i = 0; i < 16; i++) {
        int q = t + 256 * i;                 // float4 index within slice
        int lw = q >> 4, sh = (q & 15) * 4;
        u64 pw = P[lw];
        u32 np_ = (u32)(pw >> sh) & 0xFu;
        u32 ne  = (u32)((E[lw] & ~pw) >> sh) & 0xFu;
        u32 nf  = (u32)((F[lw] & ~pw) >> sh) & 0xFu;
        if (!(np_ | ne | nf)) continue;
        f4 cv = __builtin_nontemporal_load((const f4*)(cbase + q * 4));
        #pragma unroll
        for (int j = 0; j < 4; j++) {
            float cs = cv[j], rl = fmaxf(cs, 0.f);
            if ((np_ >> j) & 1) sp += 1.f - cs;
            if ((ne >> j) & 1) { se += rl; cE++; }
            if ((nf >> j) & 1) { sf += rl; cF++; }
        }
    }
    int lane = t & 63, wid = t >> 6;
    double vals[5] = {(double)sp, (double)se, (double)cE, (double)sf, (double)cF};
    #pragma unroll
    for (int i = 0; i < 5; i++) {
        double x = wave_red(vals[i]);
        if (lane == 0) red[wid][i] = x;
    }
    __syncthreads();
    if (t < 5) {
        double sum = red[0][t] + red[1][t] + red[2][t] + red[3][t];
        atomicAdd(&acc[26 + t], sum);
    }
}

// ---- combine into the scalar loss ----
__global__ void k_combine(const double* __restrict__ acc, float* __restrict__ out) {
    if (threadIdx.x != 0 || blockIdx.x != 0) return;
    double ce = acc[19] / (double)NVOX;
    double dcl = 0;
    for (int c = 1; c <= 2; c++) {
        double T = acc[23 + c], S = acc[20 + c], N = acc[16 + c];
        dcl += (2.0 * T + 1e-5) / fmax(S + N + 1e-5, 1e-8);
    }
    double dc_loss = -(dcl / 2.0);
    double cnt = acc[17];
    double pl = (cnt > 0.0) ? acc[26] / fmax(cnt, 1.0) : 0.0;
    double ml = (acc[28] > 0.0) ? acc[27] / acc[28] : 0.0;
    double nl = (acc[30] > 0.0) ? acc[29] / acc[30] : 0.0;
    out[0] = (float)(ce + dc_loss + 5.0 * (pl + ml + nl));
}

extern "C" void kernel_launch(void* const* d_in, const int* in_sizes, int n_in,
                              void* d_out, int out_size, void* d_ws, size_t ws_size,
                              hipStream_t stream)
{
    const float* feat = (const float*)d_in[0];
    const float* net  = (const float*)d_in[1];
    const int*   tgt  = (const int*)d_in[2];
    float* out = (float*)d_out;
    char* w = (char*)d_ws;

    double* acc  = (double*)(w + ACC_OFF);
    float* stdn  = (float*)(w + STD_OFF);
    u32* scan    = (u32*)(w + SCAN_OFF);
    u32* hist    = (u32*)(w + HIST_OFF);
    u64* hib     = (u64*)(w + HIB_OFF);
    u64* posb    = (u64*)(w + POSB_OFF);
    u64* negb    = (u64*)(w + NEGB_OFF);
    u64* dtmp    = (u64*)(w + DTMP_OFF);
    u64* cand    = (u64*)(w + CAND_OFF);
    float* cosm  = (float*)(w + COS_OFF);

    hipMemsetAsync(w, 0, ZERO_BYTES, stream);

    k_main   <<<2048, 256, 0, stream>>>(feat, net, tgt, posb, negb, acc);
    k_std    <<<1,    64,  0, stream>>>(acc, stdn);
    k_cos    <<<2048, 256, 0, stream>>>(feat, stdn, negb, cosm, hist);
    k_scanA  <<<1,    256, 0, stream>>>(hist, scan);
    k_collect<<<2048, 256, 0, stream>>>(cosm, negb, scan, cand);
    k_select <<<1,    256, 0, stream>>>(cand, scan, hib);
    k_dilD   <<<512,  256, 0, stream>>>(posb, hib, dtmp);
    k_dilfin <<<256,  256, 0, stream>>>(dtmp, posb, cosm, acc);
    k_combine<<<1,    64,  0, stream>>>(acc, out);
}